// Round 1
// baseline (918.050 us; speedup 1.0000x reference)
//
#include <hip/hip_runtime.h>

#pragma clang fp contract(off)

// Problem constants
#define NB 16      // N
#define NRR 300    // NR == NR_SO
#define KTOP 10    // K

// Output layout (float offsets)
#define OFF_PRO 0
#define OFF_BOX 2621440
#define OFF_CLS 2662400
#define OFF_REL 4198400
#define OFF_ROI 5509120
#define OFF_VIS 69734400

// float4 / float2 offsets
#define OFF_BOX4 655360
#define OFF_CLS4 665600
#define OFF_REL4 1049600
#define OFF_ROI4 1377280
#define OFF_CLS2 1331200

#define NC 4080                 // copy blocks in k_main
#define MAIN_TOT 16344000u      // float4 elements in the main (rows 0..299) copy

__device__ __forceinline__ float sigm(float x){ return 1.0f/(1.0f + expf(-x)); }

// ---------------------------------------------------------------------------
// k_main: blocks 0..15 = full control path for batch n (pair top-3, triple
// top-100, entity IoU-dedup scores, entity top-10, vis_out). Blocks 16.. =
// main copy of rows 0..299 of all five outputs (no dependence on ent), which
// runs CONCURRENTLY with the control blocks on the remaining CUs.
// ---------------------------------------------------------------------------
__global__ __launch_bounds__(512) void k_main(
    const float* __restrict__ so_cls, const float* __restrict__ rel_logits,
    const float* __restrict__ class_logits, const float* __restrict__ pred_bboxes,
    const float* __restrict__ pbso, const unsigned char* __restrict__ vis,
    const float4* __restrict__ so_roi4, const float4* __restrict__ so_pro4,
    const float4* __restrict__ so_cls4, const float4* __restrict__ rel_feat4,
    const float4* __restrict__ pbso4,
    float* __restrict__ out, float4* __restrict__ out4,
    int* __restrict__ ent)
{
  __shared__ unsigned long long keys[4096];   // 32768 B (reused by top10 sort)
  __shared__ float s_sc[NRR][3], o_sc[NRR][3];
  __shared__ short s_cl[NRR][3], o_cl[NRR][3];
  __shared__ float rmax[NRR];
  __shared__ int   sidx[128];
  __shared__ int   selc[200];
  __shared__ float selb[200][4];
  __shared__ float escore[NRR];
  __shared__ int   entl[16];

  const int tid = threadIdx.x;

  if (blockIdx.x >= 16) {
    // ------------------- main copy (rows 0..299, contiguous per batch) -----
    unsigned gtid   = (blockIdx.x - 16) * 512u + (unsigned)tid;
    unsigned stride = (gridDim.x - 16) * 512u;
    for (unsigned i = gtid; i < MAIN_TOT; i += stride) {
      if (i < 15052800u) {                              // ROI: 16 x 940800 f4
        unsigned n = i / 940800u, c = i - n*940800u;
        out4[OFF_ROI4 + n*1003520u + c] = so_roi4[n*940800u + c];
      } else if (i < 15667200u) {                       // PRO: 16 x 38400 f4
        unsigned j = i - 15052800u;
        unsigned n = j / 38400u, c = j - n*38400u;
        out4[n*40960u + c] = so_pro4[n*38400u + c];
      } else if (i < 16027200u) {                       // CLS: 16 x 22500 f4
        unsigned j = i - 15667200u;
        unsigned n = j / 22500u, c = j - n*22500u;
        out4[OFF_CLS4 + n*24000u + c] = so_cls4[n*22500u + c];
      } else if (i < 16334400u) {                       // REL: 16 x 19200 f4
        unsigned j = i - 16027200u;
        unsigned n = j / 19200u, c = j - n*19200u;
        out4[OFF_REL4 + n*20480u + c] = rel_feat4[n*19200u + c];
      } else {                                          // BOX: 16 x 600 f4
        unsigned j = i - 16334400u;
        unsigned n = j / 600u, c = j - n*600u;
        out4[OFF_BOX4 + n*640u + c] = pbso4[n*600u + c];
      }
    }
    return;
  }

  // ---------------------------- control path -----------------------------
  const int n = blockIdx.x;
  const int w = tid >> 6, lane = tid & 63;

  // Phase A: per pair, top-3 of each 150-logit half (tie -> lowest index)
  // and rel_max. One wave per pair, 8 waves round-robin.
  for (int k = w; k < NRR; k += 8) {
    const float* row = so_cls + (size_t)(n*NRR + k) * 300;
    for (int half = 0; half < 2; ++half) {
      const float* r = row + half * 150;
      float v[3]; int ci[3];
      #pragma unroll
      for (int j = 0; j < 3; ++j) {
        int c = lane + j * 64;
        ci[j] = c;
        v[j]  = (c < 150) ? r[c] : -1e38f;
      }
      for (int rd = 0; rd < 3; ++rd) {
        float bv = v[0]; int bi = ci[0];
        if (v[1] > bv) { bv = v[1]; bi = ci[1]; }
        if (v[2] > bv) { bv = v[2]; bi = ci[2]; }
        #pragma unroll
        for (int off = 32; off >= 1; off >>= 1) {
          float ov = __shfl_xor(bv, off, 64);
          int   oi = __shfl_xor(bi, off, 64);
          if (ov > bv || (ov == bv && oi < bi)) { bv = ov; bi = oi; }
        }
        if (lane == 0) {
          if (half) { o_sc[k][rd] = sigm(bv); o_cl[k][rd] = (short)bi; }
          else      { s_sc[k][rd] = sigm(bv); s_cl[k][rd] = (short)bi; }
        }
        #pragma unroll
        for (int j = 0; j < 3; ++j) if (ci[j] == bi) v[j] = -1e38f;
      }
    }
    float m = (lane < 50) ? rel_logits[(size_t)(n*NRR + k)*50 + lane] : -1e38f;
    #pragma unroll
    for (int off = 32; off >= 1; off >>= 1) m = fmaxf(m, __shfl_xor(m, off, 64));
    if (lane == 0) rmax[k] = sigm(m);
  }
  __syncthreads();

  // Phase B: 2700 triple scores -> bitonic sort desc of (valbits, ~flatidx)
  for (int f = tid; f < 4096; f += 512) {
    unsigned long long key = 0ull;
    if (f < 2700) {
      int k = f / 9, p = f - k * 9;
      float v = (rmax[k] * s_sc[k][p/3]) * o_sc[k][p - (p/3)*3];  // left-assoc
      key = ((unsigned long long)__float_as_uint(v) << 32)
          | (unsigned long long)(0xFFFFFFFFu - (unsigned)f);
    }
    keys[f] = key;
  }
  __syncthreads();
  for (int k = 2; k <= 4096; k <<= 1) {
    for (int j = k >> 1; j > 0; j >>= 1) {
      for (int i = tid; i < 4096; i += 512) {
        int l = i ^ j;
        if (l > i) {
          unsigned long long a = keys[i], b = keys[l];
          bool up = ((i & k) == 0);
          if ((a < b) == up) { keys[i] = b; keys[l] = a; }
        }
      }
      __syncthreads();
    }
  }

  // Phase C: top-100 flat indices, sorted ascending; emit sel_class/sel_boxes
  if (tid < 128)
    sidx[tid] = (tid < 100) ? (int)(0xFFFFFFFFu - (unsigned)(keys[tid] & 0xFFFFFFFFull))
                            : 0x7FFFFFFF;
  __syncthreads();
  for (int k = 2; k <= 128; k <<= 1) {
    for (int j = k >> 1; j > 0; j >>= 1) {
      if (tid < 64) {
        for (int i = tid; i < 128; i += 64) {
          int l = i ^ j;
          if (l > i) {
            int a = sidx[i], b = sidx[l];
            bool up = ((i & k) == 0);
            if ((a > b) == up) { sidx[i] = b; sidx[l] = a; }
          }
        }
      }
      __syncthreads();
    }
  }
  if (tid < 200) {
    int m = tid, j2 = m >> 1, side = m & 1;
    int f = sidx[j2];
    int k2 = f / 9, p = f - k2 * 9;
    selc[m] = side ? (int)o_cl[k2][p - (p/3)*3] : (int)s_cl[k2][p/3];
    const float4 b = *(const float4*)(pbso + (size_t)(n*NRR + k2)*8 + side*4);
    selb[m][0] = b.x; selb[m][1] = b.y; selb[m][2] = b.z; selb[m][3] = b.w;
  }
  __syncthreads();

  // Phase D: entity argmax + IoU dedup vs 200 selected; one wave per entity
  for (int i = w; i < NRR; i += 8) {
    const float* r = class_logits + (size_t)(n*600 + 2*i) * 150;
    float bv = r[lane]; int bi = lane;
    for (int c = lane + 64; c < 150; c += 64) {
      float x = r[c];
      if (x > bv) { bv = x; bi = c; }
    }
    #pragma unroll
    for (int off = 32; off >= 1; off >>= 1) {
      float ov = __shfl_xor(bv, off, 64);
      int   oi = __shfl_xor(bi, off, 64);
      if (ov > bv || (ov == bv && oi < bi)) { bv = ov; bi = oi; }
    }
    float maxp = sigm(bv);

    const float* b1 = pred_bboxes + (size_t)(n*600 + 2*i) * 4;
    float x1 = b1[0], y1 = b1[1], x2 = b1[2], y2 = b1[3];
    float a1 = (y2 - y1 + 1.0f) * (x2 - x1 + 1.0f);

    bool hit = false;
    for (int m = lane; m < 200; m += 64) {
      if (selc[m] == bi) {
        float a2 = (selb[m][3] - selb[m][1] + 1.0f) * (selb[m][2] - selb[m][0] + 1.0f);
        float ww = fminf(x2, selb[m][2]) - fmaxf(x1, selb[m][0]); if (ww < 0.f) ww = 0.f;
        float hh = fminf(y2, selb[m][3]) - fmaxf(y1, selb[m][1]); if (hh < 0.f) hh = 0.f;
        float inter = ww * hh;
        float iou = inter / ((a1 + a2) - inter);
        if (iou >= 0.5f) hit = true;
      }
    }
    bool any = (__ballot(hit) != 0ull);
    if (lane == 0)
      escore[i] = maxp - (any ? 2.0f : 0.0f) - (vis[n*NRR + i] ? 2.0f : 0.0f);
  }
  __syncthreads();

  // Phase E: entity top-10 (tie -> lowest idx), ascending; ent + vis_out
  {
    unsigned long long key = 0ull;
    if (tid < NRR) {
      unsigned u = __float_as_uint(escore[tid]);
      u = (u & 0x80000000u) ? ~u : (u | 0x80000000u);   // order-preserving map
      key = ((unsigned long long)u << 32)
          | (unsigned long long)(0xFFFFFFFFu - (unsigned)tid);
    }
    keys[tid] = key;
  }
  __syncthreads();
  for (int k = 2; k <= 512; k <<= 1) {
    for (int j = k >> 1; j > 0; j >>= 1) {
      {
        int i = tid, l = i ^ j;
        if (l > i) {
          unsigned long long a = keys[i], b = keys[l];
          bool up = ((i & k) == 0);
          if ((a < b) == up) { keys[i] = b; keys[l] = a; }
        }
      }
      __syncthreads();
    }
  }
  if (tid == 0) {
    int tmp[10];
    for (int j = 0; j < 10; ++j)
      tmp[j] = (int)(0xFFFFFFFFu - (unsigned)(keys[j] & 0xFFFFFFFFull));
    for (int a = 1; a < 10; ++a) {            // ascending insertion sort
      int x = tmp[a], b = a - 1;
      while (b >= 0 && tmp[b] > x) { tmp[b+1] = tmp[b]; --b; }
      tmp[b+1] = x;
    }
    for (int j = 0; j < 10; ++j) { entl[j] = tmp[j]; ent[n*KTOP + j] = tmp[j]; }
  }
  __syncthreads();
  for (int i = tid; i < NRR; i += 512) {
    bool m = vis[n*NRR + i] != 0;
    #pragma unroll
    for (int j = 0; j < 10; ++j) m = m || (entl[j] == i);
    out[OFF_VIS + n*NRR + i] = m ? 1.0f : 0.0f;
  }
}

// ---------------------------------------------------------------------------
// k_gather: the small ent-dependent tail — rows 300..319 of all five outputs.
// One item per thread, segmented flat index space (~1.1M items, ~34 MB traffic).
// ---------------------------------------------------------------------------
__global__ __launch_bounds__(256) void k_gather(
    const float4* __restrict__ roi4, const float4* __restrict__ pro4,
    const float4* __restrict__ aux4, const float4* __restrict__ cls4,
    const float2* __restrict__ cls2, const float4* __restrict__ box4,
    float4* __restrict__ out4, float2* __restrict__ out2,
    const int* __restrict__ ent)
{
  unsigned t = blockIdx.x * 256u + threadIdx.x;
  if (t < 1003520u) {                         // ROI rows 300..319 (f4)
    unsigned n = t / 62720u, rem = t - n*62720u;
    unsigned r = rem / 3136u, c = rem - r*3136u;
    int e = ent[n*KTOP + (r < 10u ? r : r - 10u)];
    unsigned cc = (r < 10u) ? c : (c >= 1568u ? c - 1568u : c + 1568u);
    out4[OFF_ROI4 + (n*320u + 300u + r)*3136u + c] = roi4[(n*300u + (unsigned)e)*3136u + cc];
  } else if (t < 1044480u) {                  // PRO rows 300..319 (f4)
    unsigned j = t - 1003520u;
    unsigned n = j / 2560u, rem = j - n*2560u;
    unsigned r = rem / 128u, c = rem - r*128u;
    int e = ent[n*KTOP + (r < 10u ? r : r - 10u)];
    unsigned cc = (r < 10u) ? c : (c >= 64u ? c - 64u : c + 64u);
    out4[(n*320u + 300u + r)*128u + c] = pro4[(n*300u + (unsigned)e)*128u + cc];
  } else if (t < 1064960u) {                  // REL rows 300..319 (f4)
    unsigned j = t - 1044480u;
    unsigned n = j / 1280u, rem = j - n*1280u;
    unsigned r = rem / 64u, c = rem - r*64u;
    int e = ent[n*KTOP + (r < 10u ? r : r - 10u)];
    unsigned cc = (r < 10u) ? c : 64u + c;
    out4[OFF_REL4 + (n*320u + 300u + r)*64u + c] = aux4[(n*300u + (unsigned)e)*128u + cc];
  } else if (t < 1076960u) {                  // CLS rows 300..309 (f4, no swap)
    unsigned j = t - 1064960u;
    unsigned n = j / 750u, rem = j - n*750u;
    unsigned r = rem / 75u, c = rem - r*75u;
    int e = ent[n*KTOP + r];
    out4[OFF_CLS4 + (n*320u + 300u + r)*75u + c] = cls4[(n*300u + (unsigned)e)*75u + c];
  } else if (t < 1100960u) {                  // CLS rows 310..319 (f2, swapped)
    unsigned j = t - 1076960u;
    unsigned n = j / 1500u, rem = j - n*1500u;
    unsigned r = rem / 150u, c = rem - r*150u;
    int e = ent[n*KTOP + r];
    unsigned cc = (c >= 75u) ? c - 75u : c + 75u;
    out2[OFF_CLS2 + (n*320u + 310u + r)*150u + c] = cls2[(n*300u + (unsigned)e)*150u + cc];
  } else if (t < 1101600u) {                  // BOX rows 300..319 (f4)
    unsigned j = t - 1100960u;
    unsigned n = j / 40u, rem = j - n*40u;
    unsigned r = rem / 2u, c = rem & 1u;
    int e = ent[n*KTOP + (r < 10u ? r : r - 10u)];
    unsigned cc = (r < 10u) ? c : (c ^ 1u);
    out4[OFF_BOX4 + (n*320u + 300u + r)*2u + c] = box4[(n*300u + (unsigned)e)*2u + cc];
  }
}

// ---------------------------------------------------------------------------
extern "C" void kernel_launch(void* const* d_in, const int* in_sizes, int n_in,
                              void* d_out, int out_size, void* d_ws, size_t ws_size,
                              hipStream_t stream) {
  const float* aux_rel        = (const float*)d_in[0];
  const float* class_logits   = (const float*)d_in[1];
  const float* pred_bboxes    = (const float*)d_in[2];
  const float* pro_features   = (const float*)d_in[3];
  const float* roi_features   = (const float*)d_in[4];
  const float* so_cls         = (const float*)d_in[5];
  const float* pred_bboxes_so = (const float*)d_in[6];
  const float* so_pro         = (const float*)d_in[7];
  const float* so_roi         = (const float*)d_in[8];
  const float* rel_logits     = (const float*)d_in[9];
  const float* rel_feat       = (const float*)d_in[10];
  const unsigned char* vis    = (const unsigned char*)d_in[11];
  float* out = (float*)d_out;
  int*   ent = (int*)d_ws;      // 16*10 ints

  // Single launch: 16 control blocks + NC streaming-copy blocks, overlapped.
  k_main<<<16 + NC, 512, 0, stream>>>(
      so_cls, rel_logits, class_logits, pred_bboxes, pred_bboxes_so, vis,
      (const float4*)so_roi, (const float4*)so_pro, (const float4*)so_cls,
      (const float4*)rel_feat, (const float4*)pred_bboxes_so,
      out, (float4*)out, ent);

  // Small ent-dependent gather tail (rows 300..319 of all outputs).
  k_gather<<<4304, 256, 0, stream>>>(
      (const float4*)roi_features, (const float4*)pro_features,
      (const float4*)aux_rel, (const float4*)class_logits,
      (const float2*)class_logits, (const float4*)pred_bboxes,
      (float4*)out, (float2*)out, ent);
}

// Round 2
// 639.716 us; speedup vs baseline: 1.4351x; 1.4351x over previous
//
#include <hip/hip_runtime.h>

#pragma clang fp contract(off)

// Problem constants
#define NB 16      // N
#define NRR 300    // NR == NR_SO
#define KTOP 10    // K

// Output layout (float offsets)
#define OFF_PRO 0
#define OFF_BOX 2621440
#define OFF_CLS 2662400
#define OFF_REL 4198400
#define OFF_ROI 5509120
#define OFF_VIS 69734400

// float4 / float2 offsets
#define OFF_BOX4 655360
#define OFF_CLS4 665600
#define OFF_REL4 1049600
#define OFF_ROI4 1377280
#define OFF_CLS2 1331200

// Main (ent-independent, rows 0..299) copy: flat float4 index space split
// across the four control dispatches as ballast.
#define MAIN_TOT 16344000u
#define CP0_HI    4200000u     // k_pair   carries [0, 4.2M)
#define CP1_HI   10200000u     // k_tri100 carries [4.2M, 10.2M)
#define CP2_HI   14000000u     // k_entity carries [10.2M, 14.0M)
                               // k_top10  carries [14.0M, MAIN_TOT)

#define PAIR_CTRL 1200
#define ENT_CTRL  1200
#define TRI_CTRL  16
#define TOP_CTRL  16

#define PAIR_COPYB 3072
#define TRI_COPYB  1536
#define ENT_COPYB  3072
#define TOP_COPYB  3072

__device__ __forceinline__ float sigm(float x){ return 1.0f/(1.0f + expf(-x)); }

// Shared ent-independent copy (verified absmax=0 in round 1).
__device__ __forceinline__ void copy_range(
    unsigned lo, unsigned hi, unsigned t, unsigned nt,
    const float4* __restrict__ so_roi4, const float4* __restrict__ so_pro4,
    const float4* __restrict__ so_cls4, const float4* __restrict__ rel_feat4,
    const float4* __restrict__ pbso4, float4* __restrict__ out4)
{
  for (unsigned i = lo + t; i < hi; i += nt) {
    if (i < 15052800u) {                              // ROI: 16 x 940800 f4
      unsigned n = i / 940800u, c = i - n*940800u;
      out4[OFF_ROI4 + n*1003520u + c] = so_roi4[n*940800u + c];
    } else if (i < 15667200u) {                       // PRO: 16 x 38400 f4
      unsigned j = i - 15052800u;
      unsigned n = j / 38400u, c = j - n*38400u;
      out4[n*40960u + c] = so_pro4[n*38400u + c];
    } else if (i < 16027200u) {                       // CLS: 16 x 22500 f4
      unsigned j = i - 15667200u;
      unsigned n = j / 22500u, c = j - n*22500u;
      out4[OFF_CLS4 + n*24000u + c] = so_cls4[n*22500u + c];
    } else if (i < 16334400u) {                       // REL: 16 x 19200 f4
      unsigned j = i - 16027200u;
      unsigned n = j / 19200u, c = j - n*19200u;
      out4[OFF_REL4 + n*20480u + c] = rel_feat4[n*19200u + c];
    } else {                                          // BOX: 16 x 600 f4
      unsigned j = i - 16334400u;
      unsigned n = j / 600u, c = j - n*600u;
      out4[OFF_BOX4 + n*640u + c] = pbso4[n*600u + c];
    }
  }
}

// ---------------------------------------------------------------------------
// Kernel A: blocks [0,1200) = one wave per (n,pair): top-3 subject/object
// probs+classes (tie -> lowest index) and rel_max. Blocks >=1200: copy chunk 0.
// ---------------------------------------------------------------------------
__global__ __launch_bounds__(256) void k_pair(
    const float* __restrict__ so_cls, const float* __restrict__ rel_logits,
    float* __restrict__ s_score, int* __restrict__ s_class,
    float* __restrict__ o_score, int* __restrict__ o_class,
    float* __restrict__ relmax,
    const float4* __restrict__ so_roi4, const float4* __restrict__ so_pro4,
    const float4* __restrict__ so_cls4, const float4* __restrict__ rel_feat4,
    const float4* __restrict__ pbso4, float4* __restrict__ out4)
{
  if (blockIdx.x >= PAIR_CTRL) {
    unsigned t  = (blockIdx.x - PAIR_CTRL) * 256u + threadIdx.x;
    unsigned nt = (gridDim.x - PAIR_CTRL) * 256u;
    copy_range(0u, CP0_HI, t, nt, so_roi4, so_pro4, so_cls4, rel_feat4, pbso4, out4);
    return;
  }
  int wid  = (blockIdx.x * 256 + threadIdx.x) >> 6;
  int lane = threadIdx.x & 63;
  if (wid >= NB * NRR) return;
  const float* row = so_cls + (size_t)wid * 300;

  for (int half = 0; half < 2; ++half) {
    const float* r = row + half * 150;
    float v[3]; int ci[3];
    #pragma unroll
    for (int j = 0; j < 3; ++j) {
      int c = lane + j * 64;
      ci[j] = c;
      v[j]  = (c < 150) ? r[c] : -1e38f;
    }
    float* ss = half ? o_score : s_score;
    int*   sc = half ? o_class : s_class;
    for (int rd = 0; rd < 3; ++rd) {
      float bv = v[0]; int bi = ci[0];
      if (v[1] > bv) { bv = v[1]; bi = ci[1]; }
      if (v[2] > bv) { bv = v[2]; bi = ci[2]; }
      #pragma unroll
      for (int off = 32; off >= 1; off >>= 1) {
        float ov = __shfl_xor(bv, off, 64);
        int   oi = __shfl_xor(bi, off, 64);
        if (ov > bv || (ov == bv && oi < bi)) { bv = ov; bi = oi; }
      }
      if (lane == 0) { ss[wid*3 + rd] = sigm(bv); sc[wid*3 + rd] = bi; }
      #pragma unroll
      for (int j = 0; j < 3; ++j) if (ci[j] == bi) v[j] = -1e38f;
    }
  }
  float m = (lane < 50) ? rel_logits[(size_t)wid * 50 + lane] : -1e38f;
  #pragma unroll
  for (int off = 32; off >= 1; off >>= 1) m = fmaxf(m, __shfl_xor(m, off, 64));
  if (lane == 0) relmax[wid] = sigm(m);
}

// ---------------------------------------------------------------------------
// Kernel B: blocks [0,16) = exact top-100 of 2700 triple scores (bitonic,
// desc value, lowest idx on tie), then ascending index sort; emit sel_class
// (200) + sel_boxes (200x4). Blocks >=16: copy chunk 1. 512 threads.
// ---------------------------------------------------------------------------
__global__ __launch_bounds__(512) void k_tri100(
    const float* __restrict__ s_score, const int* __restrict__ s_class,
    const float* __restrict__ o_score, const int* __restrict__ o_class,
    const float* __restrict__ relmax,  const float* __restrict__ pbso,
    int* __restrict__ sel_class, float* __restrict__ sel_boxes,
    const float4* __restrict__ so_roi4, const float4* __restrict__ so_pro4,
    const float4* __restrict__ so_cls4, const float4* __restrict__ rel_feat4,
    const float4* __restrict__ pbso4, float4* __restrict__ out4)
{
  __shared__ unsigned long long keys[4096];
  __shared__ int sidx[128];

  if (blockIdx.x >= TRI_CTRL) {
    unsigned t  = (blockIdx.x - TRI_CTRL) * 512u + threadIdx.x;
    unsigned nt = (gridDim.x - TRI_CTRL) * 512u;
    copy_range(CP0_HI, CP1_HI, t, nt, so_roi4, so_pro4, so_cls4, rel_feat4, pbso4, out4);
    return;
  }
  int n = blockIdx.x, tid = threadIdx.x;

  for (int f = tid; f < 4096; f += 512) {
    unsigned long long key = 0ull;
    if (f < 2700) {
      int k = f / 9, p = f - k * 9;
      float s = s_score[(n*NRR + k)*3 + p/3];
      float o = o_score[(n*NRR + k)*3 + (p - (p/3)*3)];
      float v = (relmax[n*NRR + k] * s) * o;   // left-assoc, matches reference
      key = ((unsigned long long)__float_as_uint(v) << 32)
          | (unsigned long long)(0xFFFFFFFFu - (unsigned)f);
    }
    keys[f] = key;
  }
  __syncthreads();
  for (int k = 2; k <= 4096; k <<= 1) {
    for (int j = k >> 1; j > 0; j >>= 1) {
      for (int i = tid; i < 4096; i += 512) {
        int l = i ^ j;
        if (l > i) {
          unsigned long long a = keys[i], b = keys[l];
          bool up = ((i & k) == 0);
          if ((a < b) == up) { keys[i] = b; keys[l] = a; }
        }
      }
      __syncthreads();
    }
  }
  if (tid < 128)
    sidx[tid] = (tid < 100) ? (int)(0xFFFFFFFFu - (unsigned)(keys[tid] & 0xFFFFFFFFull))
                            : 0x7FFFFFFF;
  __syncthreads();
  for (int k = 2; k <= 128; k <<= 1) {
    for (int j = k >> 1; j > 0; j >>= 1) {
      if (tid < 64) {
        for (int i = tid; i < 128; i += 64) {
          int l = i ^ j;
          if (l > i) {
            int a = sidx[i], b = sidx[l];
            bool up = ((i & k) == 0);
            if ((a > b) == up) { sidx[i] = b; sidx[l] = a; }
          }
        }
      }
      __syncthreads();
    }
  }
  if (tid < 200) {
    int m = tid, j = m >> 1, side = m & 1;
    int f = sidx[j];
    int k2 = f / 9, p = f - k2 * 9;
    sel_class[n*200 + m] = side ? o_class[(n*NRR + k2)*3 + (p - (p/3)*3)]
                                : s_class[(n*NRR + k2)*3 + p/3];
    const float4 b = *(const float4*)(pbso + (size_t)(n*NRR + k2)*8 + side*4);
    *(float4*)(sel_boxes + (size_t)(n*200 + m)*4) = b;
  }
}

// ---------------------------------------------------------------------------
// Kernel C: blocks [0,1200) = one wave per (n,entity): argmax class, IoU-dedup
// vs 200 selected, entity score. Blocks >=1200: copy chunk 2.
// ---------------------------------------------------------------------------
__global__ __launch_bounds__(256) void k_entity(
    const float* __restrict__ class_logits, const float* __restrict__ pred_bboxes,
    const int* __restrict__ sel_class, const float* __restrict__ sel_boxes,
    const unsigned char* __restrict__ vis, float* __restrict__ score,
    const float4* __restrict__ so_roi4, const float4* __restrict__ so_pro4,
    const float4* __restrict__ so_cls4, const float4* __restrict__ rel_feat4,
    const float4* __restrict__ pbso4, float4* __restrict__ out4)
{
  if (blockIdx.x >= ENT_CTRL) {
    unsigned t  = (blockIdx.x - ENT_CTRL) * 256u + threadIdx.x;
    unsigned nt = (gridDim.x - ENT_CTRL) * 256u;
    copy_range(CP1_HI, CP2_HI, t, nt, so_roi4, so_pro4, so_cls4, rel_feat4, pbso4, out4);
    return;
  }
  int wid  = (blockIdx.x * 256 + threadIdx.x) >> 6;
  int lane = threadIdx.x & 63;
  if (wid >= NB * NRR) return;
  int n = wid / NRR, i = wid - n * NRR;

  const float* r = class_logits + (size_t)(n*600 + 2*i) * 150;
  float bv = r[lane]; int bi = lane;
  for (int c = lane + 64; c < 150; c += 64) {
    float x = r[c];
    if (x > bv) { bv = x; bi = c; }
  }
  #pragma unroll
  for (int off = 32; off >= 1; off >>= 1) {
    float ov = __shfl_xor(bv, off, 64);
    int   oi = __shfl_xor(bi, off, 64);
    if (ov > bv || (ov == bv && oi < bi)) { bv = ov; bi = oi; }
  }
  float maxp = sigm(bv);

  const float* b1 = pred_bboxes + (size_t)(n*600 + 2*i) * 4;
  float x1 = b1[0], y1 = b1[1], x2 = b1[2], y2 = b1[3];
  float a1 = (y2 - y1 + 1.0f) * (x2 - x1 + 1.0f);

  bool hit = false;
  for (int m = lane; m < 200; m += 64) {
    if (sel_class[n*200 + m] == bi) {
      const float4 b2 = *(const float4*)(sel_boxes + (size_t)(n*200 + m)*4);
      float a2 = (b2.w - b2.y + 1.0f) * (b2.z - b2.x + 1.0f);
      float w = fminf(x2, b2.z) - fmaxf(x1, b2.x); if (w < 0.f) w = 0.f;
      float h = fminf(y2, b2.w) - fmaxf(y1, b2.y); if (h < 0.f) h = 0.f;
      float inter = w * h;
      float iou = inter / ((a1 + a2) - inter);
      if (iou >= 0.5f) hit = true;
    }
  }
  bool any = (__ballot(hit) != 0ull);
  if (lane == 0)
    score[wid] = maxp - (any ? 2.0f : 0.0f) - (vis[n*NRR + i] ? 2.0f : 0.0f);
}

// ---------------------------------------------------------------------------
// Kernel D: blocks [0,16) = top-10 entity indices (tie -> lowest idx), sorted
// ascending; writes ent + vis_out. Blocks >=16: copy chunk 3.
// ---------------------------------------------------------------------------
__global__ __launch_bounds__(256) void k_top10(
    const float* __restrict__ score, const unsigned char* __restrict__ vis,
    int* __restrict__ ent, float* __restrict__ vis_out,
    const float4* __restrict__ so_roi4, const float4* __restrict__ so_pro4,
    const float4* __restrict__ so_cls4, const float4* __restrict__ rel_feat4,
    const float4* __restrict__ pbso4, float4* __restrict__ out4)
{
  __shared__ unsigned long long keys[512];
  __shared__ int top[16];

  if (blockIdx.x >= TOP_CTRL) {
    unsigned t  = (blockIdx.x - TOP_CTRL) * 256u + threadIdx.x;
    unsigned nt = (gridDim.x - TOP_CTRL) * 256u;
    copy_range(CP2_HI, MAIN_TOT, t, nt, so_roi4, so_pro4, so_cls4, rel_feat4, pbso4, out4);
    return;
  }
  int n = blockIdx.x, tid = threadIdx.x;

  for (int i = tid; i < 512; i += 256) {
    unsigned long long key = 0ull;
    if (i < NRR) {
      unsigned u = __float_as_uint(score[n*NRR + i]);
      u = (u & 0x80000000u) ? ~u : (u | 0x80000000u);   // order-preserving map
      key = ((unsigned long long)u << 32)
          | (unsigned long long)(0xFFFFFFFFu - (unsigned)i);
    }
    keys[i] = key;
  }
  __syncthreads();
  for (int k = 2; k <= 512; k <<= 1) {
    for (int j = k >> 1; j > 0; j >>= 1) {
      for (int i = tid; i < 512; i += 256) {
        int l = i ^ j;
        if (l > i) {
          unsigned long long a = keys[i], b = keys[l];
          bool up = ((i & k) == 0);
          if ((a < b) == up) { keys[i] = b; keys[l] = a; }
        }
      }
      __syncthreads();
    }
  }
  if (tid == 0) {
    int tmp[10];
    for (int j = 0; j < 10; ++j)
      tmp[j] = (int)(0xFFFFFFFFu - (unsigned)(keys[j] & 0xFFFFFFFFull));
    for (int a = 1; a < 10; ++a) {            // ascending insertion sort
      int x = tmp[a], b = a - 1;
      while (b >= 0 && tmp[b] > x) { tmp[b+1] = tmp[b]; --b; }
      tmp[b+1] = x;
    }
    for (int j = 0; j < 10; ++j) { top[j] = tmp[j]; ent[n*KTOP + j] = tmp[j]; }
  }
  __syncthreads();
  for (int i = tid; i < NRR; i += 256) {
    bool m = vis[n*NRR + i] != 0;
    #pragma unroll
    for (int j = 0; j < 10; ++j) m = m || (top[j] == i);
    vis_out[n*NRR + i] = m ? 1.0f : 0.0f;
  }
}

// ---------------------------------------------------------------------------
// k_gather: ent-dependent tail — rows 300..319 of all five outputs
// (verified absmax=0 in round 1).
// ---------------------------------------------------------------------------
__global__ __launch_bounds__(256) void k_gather(
    const float4* __restrict__ roi4, const float4* __restrict__ pro4,
    const float4* __restrict__ aux4, const float4* __restrict__ cls4,
    const float2* __restrict__ cls2, const float4* __restrict__ box4,
    float4* __restrict__ out4, float2* __restrict__ out2,
    const int* __restrict__ ent)
{
  unsigned t = blockIdx.x * 256u + threadIdx.x;
  if (t < 1003520u) {                         // ROI rows 300..319 (f4)
    unsigned n = t / 62720u, rem = t - n*62720u;
    unsigned r = rem / 3136u, c = rem - r*3136u;
    int e = ent[n*KTOP + (r < 10u ? r : r - 10u)];
    unsigned cc = (r < 10u) ? c : (c >= 1568u ? c - 1568u : c + 1568u);
    out4[OFF_ROI4 + (n*320u + 300u + r)*3136u + c] = roi4[(n*300u + (unsigned)e)*3136u + cc];
  } else if (t < 1044480u) {                  // PRO rows 300..319 (f4)
    unsigned j = t - 1003520u;
    unsigned n = j / 2560u, rem = j - n*2560u;
    unsigned r = rem / 128u, c = rem - r*128u;
    int e = ent[n*KTOP + (r < 10u ? r : r - 10u)];
    unsigned cc = (r < 10u) ? c : (c >= 64u ? c - 64u : c + 64u);
    out4[(n*320u + 300u + r)*128u + c] = pro4[(n*300u + (unsigned)e)*128u + cc];
  } else if (t < 1064960u) {                  // REL rows 300..319 (f4)
    unsigned j = t - 1044480u;
    unsigned n = j / 1280u, rem = j - n*1280u;
    unsigned r = rem / 64u, c = rem - r*64u;
    int e = ent[n*KTOP + (r < 10u ? r : r - 10u)];
    unsigned cc = (r < 10u) ? c : 64u + c;
    out4[OFF_REL4 + (n*320u + 300u + r)*64u + c] = aux4[(n*300u + (unsigned)e)*128u + cc];
  } else if (t < 1076960u) {                  // CLS rows 300..309 (f4, no swap)
    unsigned j = t - 1064960u;
    unsigned n = j / 750u, rem = j - n*750u;
    unsigned r = rem / 75u, c = rem - r*75u;
    int e = ent[n*KTOP + r];
    out4[OFF_CLS4 + (n*320u + 300u + r)*75u + c] = cls4[(n*300u + (unsigned)e)*75u + c];
  } else if (t < 1100960u) {                  // CLS rows 310..319 (f2, swapped)
    unsigned j = t - 1076960u;
    unsigned n = j / 1500u, rem = j - n*1500u;
    unsigned r = rem / 150u, c = rem - r*150u;
    int e = ent[n*KTOP + r];
    unsigned cc = (c >= 75u) ? c - 75u : c + 75u;
    out2[OFF_CLS2 + (n*320u + 310u + r)*150u + c] = cls2[(n*300u + (unsigned)e)*150u + cc];
  } else if (t < 1101600u) {                  // BOX rows 300..319 (f4)
    unsigned j = t - 1100960u;
    unsigned n = j / 40u, rem = j - n*40u;
    unsigned r = rem / 2u, c = rem & 1u;
    int e = ent[n*KTOP + (r < 10u ? r : r - 10u)];
    unsigned cc = (r < 10u) ? c : (c ^ 1u);
    out4[OFF_BOX4 + (n*320u + 300u + r)*2u + c] = box4[(n*300u + (unsigned)e)*2u + cc];
  }
}

// ---------------------------------------------------------------------------
extern "C" void kernel_launch(void* const* d_in, const int* in_sizes, int n_in,
                              void* d_out, int out_size, void* d_ws, size_t ws_size,
                              hipStream_t stream) {
  const float* aux_rel        = (const float*)d_in[0];
  const float* class_logits   = (const float*)d_in[1];
  const float* pred_bboxes    = (const float*)d_in[2];
  const float* pro_features   = (const float*)d_in[3];
  const float* roi_features   = (const float*)d_in[4];
  const float* so_cls         = (const float*)d_in[5];
  const float* pred_bboxes_so = (const float*)d_in[6];
  const float* so_pro         = (const float*)d_in[7];
  const float* so_roi         = (const float*)d_in[8];
  const float* rel_logits     = (const float*)d_in[9];
  const float* rel_feat       = (const float*)d_in[10];
  const unsigned char* vis    = (const unsigned char*)d_in[11];
  float* out = (float*)d_out;

  // workspace carve (floats)
  float* ws        = (float*)d_ws;
  float* s_score   = ws;                    // 16*300*3
  float* o_score   = ws + 14400;            // 16*300*3
  int*   s_class   = (int*)(ws + 28800);    // 16*300*3
  int*   o_class   = (int*)(ws + 43200);    // 16*300*3
  float* relmax    = ws + 57600;            // 16*300
  int*   sel_class = (int*)(ws + 62400);    // 16*200
  float* sel_boxes = ws + 65600;            // 16*200*4
  float* score     = ws + 78400;            // 16*300
  int*   ent       = (int*)(ws + 83200);    // 16*10

  const float4* so_roi4   = (const float4*)so_roi;
  const float4* so_pro4   = (const float4*)so_pro;
  const float4* so_cls4   = (const float4*)so_cls;
  const float4* rel_feat4 = (const float4*)rel_feat;
  const float4* pbso4     = (const float4*)pred_bboxes_so;
  float4* out4 = (float4*)out;

  k_pair  <<<PAIR_CTRL + PAIR_COPYB, 256, 0, stream>>>(
      so_cls, rel_logits, s_score, s_class, o_score, o_class, relmax,
      so_roi4, so_pro4, so_cls4, rel_feat4, pbso4, out4);
  k_tri100<<<TRI_CTRL + TRI_COPYB, 512, 0, stream>>>(
      s_score, s_class, o_score, o_class, relmax, pred_bboxes_so,
      sel_class, sel_boxes,
      so_roi4, so_pro4, so_cls4, rel_feat4, pbso4, out4);
  k_entity<<<ENT_CTRL + ENT_COPYB, 256, 0, stream>>>(
      class_logits, pred_bboxes, sel_class, sel_boxes, vis, score,
      so_roi4, so_pro4, so_cls4, rel_feat4, pbso4, out4);
  k_top10 <<<TOP_CTRL + TOP_COPYB, 256, 0, stream>>>(
      score, vis, ent, out + OFF_VIS,
      so_roi4, so_pro4, so_cls4, rel_feat4, pbso4, out4);

  // Small ent-dependent gather tail (rows 300..319 of all outputs).
  k_gather<<<4304, 256, 0, stream>>>(
      (const float4*)roi_features, (const float4*)pro_features,
      (const float4*)aux_rel, (const float4*)class_logits,
      (const float2*)class_logits, (const float4*)pred_bboxes,
      (float4*)out, (float2*)out, ent);
}